// Round 12
// baseline (74.117 us; speedup 1.0000x reference)
//
#include <hip/hip_runtime.h>

#define CCH 128      // channels
#define TLEN 2048
#define NBATCH 8
#define NATOMS 3584
#define NEG 0.2f
typedef unsigned long long ull;

// 7-bit packed index lists (up to 9 slots)
#define PK1(a) ((ull)(a))
#define PK2(a,b) (PK1(a)|((ull)(b)<<7))
#define PK3(a,b,c) (PK2(a,b)|((ull)(c)<<14))
#define PK4(a,b,c,d) (PK3(a,b,c)|((ull)(d)<<21))
// 6-bit packed (10 slots in 60 bits)
#define P6(v,k) ((ull)(v)<<(6*(k)))
#define PX10(a,b,c,d,e,f,g,h,i,j) (P6(a,0)|P6(b,1)|P6(c,2)|P6(d,3)|P6(e,4)| \
    P6(f,5)|P6(g,6)|P6(h,7)|P6(i,8)|P6(j,9))

// Per-batch unique L2 columns (union of {o-9,o,o+9} for L3 cols
// o in {18,19,45,46,72,73,99,100,126,127}), sorted:
__device__ const int g_l2cols[28] = {
    9,10,18,19,27,28,36,37,45,46,54,55,63,64,
    72,73,81,82,90,91,99,100,108,109,117,118,126,127};

__device__ __forceinline__ float lrelu(float v) { return v >= 0.f ? v : NEG * v; }
__device__ __forceinline__ float dot4(float4 w, float4 x) {
    return w.x * x.x + w.y * x.y + w.z * x.z + w.w * x.w;
}

// Touch weights to warm caches (keep-alive defeats DCE, rule #17).
__device__ __forceinline__ void warm(const float* p, int nf4, int gid, int nthr) {
    const float4* q = (const float4*)p;
    for (int i = gid; i < nf4; i += nthr) {
        float4 v = q[i];
        asm volatile("" :: "v"(v.x), "v"(v.y), "v"(v.z), "v"(v.w));
    }
}

// Reduce 4 accumulators over the 16 K-split lanes (tid = g*16+s).
__device__ __forceinline__ float red16x4(float a0, float a1, float a2, float a3, int s) {
    a0 += __shfl_xor(a0, 8); a1 += __shfl_xor(a1, 8);
    a2 += __shfl_xor(a2, 8); a3 += __shfl_xor(a3, 8);
    a0 += __shfl_xor(a0, 4); a1 += __shfl_xor(a1, 4);
    a2 += __shfl_xor(a2, 4); a3 += __shfl_xor(a3, 4);
    float u0 = (s & 2) ? a2 : a0;
    float v0 = (s & 2) ? a0 : a2;
    u0 += __shfl_xor(v0, 2);
    float u1 = (s & 2) ? a3 : a1;
    float v1 = (s & 2) ? a1 : a3;
    u1 += __shfl_xor(v1, 2);
    float w  = (s & 1) ? u1 : u0;
    float vv = (s & 1) ? u0 : u1;
    w += __shfl_xor(vv, 1);
    return w;
}

// One residual dilated block over NB scratch columns (see R7-R10 comments).
template<int NB, int SH = 7>
__device__ __forceinline__ void conv4(
        const float (*src)[CCH], float (*dst)[CCH], float* gout,
        ull pm, ull pc, ull pp, ull pd, int a0,
        const float* __restrict__ Wd, const float* __restrict__ bd,
        const float* __restrict__ Wo, const float* __restrict__ bo,
        float (*ybuf)[CCH], int g, int s)
{
    const int MSK = (1 << SH) - 1;
    const int ch = 4 * g + (s & 3);
    const float myBd = bd[ch];
    const float myBo = bo[ch];
    float4 W[24], V[8];
    {
        const float4* Wr = (const float4*)Wd + (size_t)(4 * g) * 96;
        #pragma unroll
        for (int r = 0; r < 4; ++r)
            #pragma unroll
            for (int j = 0; j < 3; ++j) {
                W[r * 6 + j]     = Wr[r * 96 + 3 * s + j];
                W[r * 6 + 3 + j] = Wr[r * 96 + 3 * s + 48 + j];
            }
        const float4* Or = (const float4*)Wo + (size_t)(4 * g) * 32;
        #pragma unroll
        for (int r = 0; r < 4; ++r) {
            V[r * 2]     = Or[r * 32 + s];
            V[r * 2 + 1] = Or[r * 32 + s + 16];
        }
    }
    __syncthreads();                     // src ready + ybuf free
    #pragma unroll
    for (int t = 0; t < NB; ++t) {
        const float* fm = src[(int)((pm >> (SH * t)) & MSK)];
        const float* fc = src[(int)((pc >> (SH * t)) & MSK)];
        const float* fp = src[(int)((pp >> (SH * t)) & MSK)];
        float4 m0 = *(const float4*)(fm + 4 * s);
        float4 m1 = *(const float4*)(fm + 4 * s + 64);
        float4 c0 = *(const float4*)(fc + 4 * s);
        float4 c1 = *(const float4*)(fc + 4 * s + 64);
        float4 p0 = *(const float4*)(fp + 4 * s);
        float4 p1 = *(const float4*)(fp + 4 * s + 64);
        float acc[4];
        #pragma unroll
        for (int r = 0; r < 4; ++r) {
            float4 wA = W[r*6+0], wB = W[r*6+1], wC = W[r*6+2];
            float a = wA.x*m0.x + wA.y*c0.x + wA.z*p0.x + wA.w*m0.y
                    + wB.x*c0.y + wB.y*p0.y + wB.z*m0.z + wB.w*c0.z
                    + wC.x*p0.z + wC.y*m0.w + wC.z*c0.w + wC.w*p0.w;
            float4 wD = W[r*6+3], wE = W[r*6+4], wF = W[r*6+5];
            float b2 = wD.x*m1.x + wD.y*c1.x + wD.z*p1.x + wD.w*m1.y
                     + wE.x*c1.y + wE.y*p1.y + wE.z*m1.z + wE.w*c1.z
                     + wF.x*p1.z + wF.y*m1.w + wF.z*c1.w + wF.w*p1.w;
            acc[r] = a + b2;
        }
        float tot = red16x4(acc[0], acc[1], acc[2], acc[3], s);
        if (s < 4) ybuf[t][ch] = tot + myBd;
    }
    __syncthreads();                     // ybuf ready
    #pragma unroll
    for (int t = 0; t < NB; ++t) {
        int jc = (int)((pc >> (SH * t)) & MSK);
        int jd = (int)((pd >> (SH * t)) & MSK);
        const float* y = ybuf[t];
        float4 y0 = *(const float4*)(y + 4 * s);
        float4 y1 = *(const float4*)(y + 4 * s + 64);
        float a0_ = dot4(V[0], y0) + dot4(V[1], y1);
        float a1_ = dot4(V[2], y0) + dot4(V[3], y1);
        float a2_ = dot4(V[4], y0) + dot4(V[5], y1);
        float a3_ = dot4(V[6], y0) + dot4(V[7], y1);
        float tot = red16x4(a0_, a1_, a2_, a3_, s);
        if (s < 4) {
            float h = lrelu(tot + myBo + src[jc][ch]);
            if (gout) gout[ch] = h;
            else      dst[jd][ch] = (a0 + jd < 128) ? h : 0.f;
        }
    }
}

// K=128 matvec stage (MLP hidden layer), R=4/S=16 mapping, lrelu.
__device__ __forceinline__ void mlp4(
        const float* hin, float* hout,
        const float* __restrict__ w, const float* __restrict__ bv,
        int g, int s)
{
    const int ch = 4 * g + (s & 3);
    const float myB = bv[ch];
    float4 V[8];
    const float4* r = (const float4*)w + (size_t)(4 * g) * 32;
    #pragma unroll
    for (int rr = 0; rr < 4; ++rr) {
        V[rr * 2]     = r[rr * 32 + s];
        V[rr * 2 + 1] = r[rr * 32 + s + 16];
    }
    __syncthreads();                     // hin ready
    float4 x0 = *(const float4*)(hin + 4 * s);
    float4 x1 = *(const float4*)(hin + 4 * s + 64);
    float a0_ = dot4(V[0], x0) + dot4(V[1], x1);
    float a1_ = dot4(V[2], x0) + dot4(V[3], x1);
    float a2_ = dot4(V[4], x0) + dot4(V[5], x1);
    float a3_ = dot4(V[6], x0) + dot4(V[7], x1);
    float tot = red16x4(a0_, a1_, a2_, a3_, s);
    if (s < 4) hout[ch] = lrelu(tot + myB);
}

struct Params {
    const float *x, *embed_w, *posamp_w, *posamp_b, *reduce_w, *reduce_b;
    const float *dil_w, *dil_b, *one_w, *one_b;
    const float *aw1, *ab1, *aw2, *ab2, *aw3, *ab3;
    const float *pw1, *pb1, *pw2, *pb2, *pw3, *pb3;
    float *l2c, *h2a;
    int  *flags;            // [0..7]: per-batch cone count; [8]: tail count
    float *out;
};

// ---------------------------------------------------------------------------
// Single fused kernel, 288 blocks x 512:
//   bid <  224 : cone  (i = bid%28 L2-col, b = bid/28) -> l2c, flag[b]++
//   bid <  232 : tail  (b = bid-224): warm tail weights, spin flag[b]==28,
//                L3->L4->L5->L6->MLPs -> h2a[b] global + pa out, flag[8]++
//   bid <  288 : head  (j = bid-232): warm aw3 rows [64j,64j+64), spin
//                flag[8]==8, compute 64 rows x 8 batches (aw3 read 1x total)
// Producer->consumer only (no barrier): producers never wait => deadlock-free;
// all 288 blocks co-resident anyway (2 blocks/CU at 32KB LDS, VGPR<=128).
// Fence pattern (relaxed atomics + __threadfence) verified correct in R4.
// ---------------------------------------------------------------------------
__global__ void __launch_bounds__(512, 2) k_fused(Params P)
{
    __shared__ float smem[8192];         // 32 KB, carved per role
    const int bid = blockIdx.x;
    const int tid = threadIdx.x;
    const int g   = tid >> 4;
    const int s   = tid & 15;

    if (bid < 224) {
        // ================= cone =================
        const int i   = bid % 28;
        const int b   = bid / 28;
        const int own = g_l2cols[i];
        const int a0  = own - 4;
        const int ch  = 4 * g + (s & 3);

        // warm own weights (split across 224 blocks -> one aggregate copy)
        {
            const int gid  = bid * 512 + tid;
            const int nthr = 224 * 512;
            warm(P.reduce_w, 2 * CCH * CCH / 4, gid, nthr);
            warm(P.dil_w, 2 * CCH * CCH * 3 / 4, gid, nthr);   // layers 0-1
            warm(P.one_w, 2 * CCH * CCH / 4, gid, nthr);
        }

        float (*A)[CCH]      = (float(*)[CCH])(smem);            // [9]
        float (*B)[CCH]      = (float(*)[CCH])(smem + 1152);     // [8]
        float (*cat)[2*CCH]  = (float(*)[2*CCH])(smem + 2176);   // [9]
        float (*ybuf)[CCH]   = (float(*)[CCH])(smem + 4480);     // [3]

        const float* xb = P.x + b * 4 * TLEN;
        for (int v = tid; v < 9 * 256; v += 512) {
            int p   = v >> 8;
            int chv = v & 255;
            int ab  = a0 + p;
            float val = 0.f;
            if (ab < 128) {
                int t = (TLEN - 128) + ab;
                if (chv < CCH) {
                    int idx = (int)xb[t];          // atom id (exact int in f32)
                    val = P.embed_w[idx * CCH + chv];
                } else {
                    int cc = chv - CCH;
                    val = P.posamp_w[2 * cc] * xb[TLEN + t]
                        + P.posamp_w[2 * cc + 1] * xb[2 * TLEN + t] + P.posamp_b[cc];
                }
            }
            cat[p][chv] = val;
        }
        float4 RW[16];
        const float4* rw = (const float4*)P.reduce_w + (size_t)(4 * g) * 64;
        #pragma unroll
        for (int r = 0; r < 4; ++r)
            #pragma unroll
            for (int j = 0; j < 4; ++j)
                RW[r * 4 + j] = rw[r * 64 + s + 16 * j];
        const float rb = P.reduce_b[ch];
        __syncthreads();

        #pragma unroll 3
        for (int t = 0; t < 9; ++t) {
            const float* sc = cat[t];
            float4 x0 = *(const float4*)(sc + 4 * s);
            float4 x1 = *(const float4*)(sc + 4 * s + 64);
            float4 x2 = *(const float4*)(sc + 4 * s + 128);
            float4 x3 = *(const float4*)(sc + 4 * s + 192);
            float a0_ = dot4(RW[0],x0)+dot4(RW[1],x1)+dot4(RW[2],x2)+dot4(RW[3],x3);
            float a1_ = dot4(RW[4],x0)+dot4(RW[5],x1)+dot4(RW[6],x2)+dot4(RW[7],x3);
            float a2_ = dot4(RW[8],x0)+dot4(RW[9],x1)+dot4(RW[10],x2)+dot4(RW[11],x3);
            float a3_ = dot4(RW[12],x0)+dot4(RW[13],x1)+dot4(RW[14],x2)+dot4(RW[15],x3);
            float tot = red16x4(a0_, a1_, a2_, a3_, s);
            if (s < 4) A[t][ch] = (a0 + t < 128) ? tot + rb : 0.f;
        }

        conv4<3>(A, B, nullptr,
                 PK3(0,3,6), PK3(1,4,7), PK3(2,5,8), PK3(1,4,7), a0,
                 P.dil_w, P.dil_b, P.one_w, P.one_b, ybuf, g, s);
        conv4<1>(B, B, P.l2c + (size_t)(b * 28 + i) * CCH,
                 PK1(1), PK1(4), PK1(7), PK1(4), a0,
                 P.dil_w + (size_t)1 * CCH * CCH * 3, P.dil_b + CCH,
                 P.one_w + (size_t)1 * CCH * CCH, P.one_b + CCH, ybuf, g, s);

        __syncthreads();                 // l2c stores drained (vmcnt before barrier)
        if (tid == 0) {
            __threadfence();             // release l2c to device scope
            __hip_atomic_fetch_add(&P.flags[b], 1, __ATOMIC_RELAXED,
                                   __HIP_MEMORY_SCOPE_AGENT);
        }
    } else if (bid < 232) {
        // ================= tail (one per batch) =================
        const int b = bid - 224;

        // warm ALL tail weights into own L2/MALL while cone computes (~1.3 MB)
        warm(P.dil_w + (size_t)2 * CCH * CCH * 3, 4 * CCH * CCH * 3 / 4, tid, 512);
        warm(P.one_w + (size_t)2 * CCH * CCH,     4 * CCH * CCH / 4,     tid, 512);
        warm(P.aw1, CCH * CCH / 4, tid, 512);
        warm(P.aw2, CCH * CCH / 4, tid, 512);
        warm(P.pw1, CCH * CCH / 4, tid, 512);
        warm(P.pw2, CCH * CCH / 4, tid, 512);

        if (tid == 0) {
            while (__hip_atomic_load(&P.flags[b], __ATOMIC_RELAXED,
                                     __HIP_MEMORY_SCOPE_AGENT) < 28)
                __builtin_amdgcn_s_sleep(2);
            __threadfence();             // acquire producers' l2c writes
        }
        __syncthreads();

        float (*E)[CCH]    = (float(*)[CCH])(smem);          // [29] 28 cols + Z
        float (*D)[CCH]    = (float(*)[CCH])(smem + 3712);   // [11]
        float (*B2)[CCH]   = (float(*)[CCH])(smem + 5120);   // [5]
        float (*C2)[CCH]   = (float(*)[CCH])(smem + 5760);   // [3]
        float* HF          = smem + 6144;                    // [128]
        float (*ybuf)[CCH] = (float(*)[CCH])(smem + 6272);   // [10]
        float* h1a         = smem + 7552;
        float* h1p         = smem + 7680;
        float* h2p         = smem + 7808;

        if (tid < CCH) { E[28][tid] = 0.f; D[10][tid] = 0.f; B2[4][tid] = 0.f; C2[2][tid] = 0.f; }
        for (int v = tid; v < 28 * 32; v += 512) {
            int col = v >> 5, f4i = v & 31;
            *(float4*)&E[col][f4i * 4] =
                *(const float4*)(P.l2c + (size_t)(b * 28 + col) * CCH + f4i * 4);
        }

        // L3 (d=9), 10 cols in one weight phase
        conv4<10, 6>(E, D, nullptr,
                 PX10(0,1,6,7,12,13,18,19,24,25),
                 PX10(2,3,8,9,14,15,20,21,26,27),
                 PX10(4,5,10,11,16,17,22,23,28,28),
                 PX10(0,1,2,3,4,5,6,7,8,9), -1000,
                 P.dil_w + (size_t)2 * CCH * CCH * 3, P.dil_b + 2 * CCH,
                 P.one_w + (size_t)2 * CCH * CCH, P.one_b + 2 * CCH, ybuf, g, s);
        // L4
        conv4<4>(D, B2, nullptr,
                 PK4(0,1,6,7), PK4(2,3,8,9), PK4(4,5,10,10), PK4(0,1,2,3), -1000,
                 P.dil_w + (size_t)3 * CCH * CCH * 3, P.dil_b + 3 * CCH,
                 P.one_w + (size_t)3 * CCH * CCH, P.one_b + 3 * CCH, ybuf, g, s);
        // L5
        conv4<2>(B2, C2, nullptr,
                 PK2(0,1), PK2(2,3), PK2(4,4), PK2(0,1), -1000,
                 P.dil_w + (size_t)4 * CCH * CCH * 3, P.dil_b + 4 * CCH,
                 P.one_w + (size_t)4 * CCH * CCH, P.one_b + 4 * CCH, ybuf, g, s);
        // L6 -> HF
        conv4<1>(C2, C2, HF,
                 PK1(0), PK1(1), PK1(2), PK1(0), -1000,
                 P.dil_w + (size_t)5 * CCH * CCH * 3, P.dil_b + 5 * CCH,
                 P.one_w + (size_t)5 * CCH * CCH, P.one_b + 5 * CCH, ybuf, g, s);

        mlp4(HF,  h1a, P.aw1, P.ab1, g, s);
        mlp4(HF,  h1p, P.pw1, P.pb1, g, s);
        mlp4(h1a, P.h2a + b * CCH, P.aw2, P.ab2, g, s);   // atom h2 -> global
        mlp4(h1p, h2p, P.pw2, P.pb2, g, s);
        __syncthreads();

        // pa head: 2 outputs
        if (tid < 64) {
            int row = tid >> 5, q = tid & 31;
            float4 w4 = *(const float4*)(P.pw3 + row * CCH + 4 * q);
            float4 xv = *(const float4*)(h2p + 4 * q);
            float acc = dot4(w4, xv);
            acc += __shfl_xor(acc, 1);
            acc += __shfl_xor(acc, 2);
            acc += __shfl_xor(acc, 4);
            acc += __shfl_xor(acc, 8);
            acc += __shfl_xor(acc, 16);
            if (q == 0) P.out[NBATCH * NATOMS + b * 2 + row] = acc + P.pb3[row];
        }
        __syncthreads();                 // h2a global store drained
        if (tid == 0) {
            __threadfence();             // release h2a
            __hip_atomic_fetch_add(&P.flags[8], 1, __ATOMIC_RELAXED,
                                   __HIP_MEMORY_SCOPE_AGENT);
        }
    } else {
        // ================= head (aw3 read once aggregate) =================
        const int j = bid - 232;         // rows [64j, 64j+64)

        warm(P.aw3 + (size_t)j * 64 * CCH, 64 * CCH / 4, tid, 512);

        if (tid == 0) {
            while (__hip_atomic_load(&P.flags[8], __ATOMIC_RELAXED,
                                     __HIP_MEMORY_SCOPE_AGENT) < 8)
                __builtin_amdgcn_s_sleep(2);
            __threadfence();             // acquire h2a
        }
        __syncthreads();

        float (*hs)[CCH] = (float(*)[CCH])smem;     // [8][128]
        if (tid < 256)
            ((float4*)hs)[tid] = ((const float4*)P.h2a)[tid];
        __syncthreads();

        const int b   = tid >> 6;        // wave-uniform batch
        const int r   = tid & 63;
        const int row = j * 64 + r;
        const float4* wr = (const float4*)(P.aw3 + (size_t)row * CCH);
        const float*  h  = hs[b];        // wave-uniform LDS broadcasts
        float s0 = 0.f, s1 = 0.f, s2 = 0.f, s3 = 0.f;
        #pragma unroll
        for (int k = 0; k < 32; k += 4) {
            s0 += dot4(wr[k],     *(const float4*)&h[4 * k]);
            s1 += dot4(wr[k + 1], *(const float4*)&h[4 * k + 4]);
            s2 += dot4(wr[k + 2], *(const float4*)&h[4 * k + 8]);
            s3 += dot4(wr[k + 3], *(const float4*)&h[4 * k + 12]);
        }
        P.out[b * NATOMS + row] = s0 + s1 + s2 + s3 + P.ab3[row];
    }
}

// ---------------------------------------------------------------------------
extern "C" void kernel_launch(void* const* d_in, const int* in_sizes, int n_in,
                              void* d_out, int out_size, void* d_ws, size_t ws_size,
                              hipStream_t stream)
{
    Params P;
    P.x        = (const float*)d_in[0];
    P.embed_w  = (const float*)d_in[1];
    P.posamp_w = (const float*)d_in[2];
    P.posamp_b = (const float*)d_in[3];
    P.reduce_w = (const float*)d_in[4];
    P.reduce_b = (const float*)d_in[5];
    P.dil_w    = (const float*)d_in[6];
    P.dil_b    = (const float*)d_in[7];
    P.one_w    = (const float*)d_in[8];
    P.one_b    = (const float*)d_in[9];
    P.aw1 = (const float*)d_in[10]; P.ab1 = (const float*)d_in[11];
    P.aw2 = (const float*)d_in[12]; P.ab2 = (const float*)d_in[13];
    P.aw3 = (const float*)d_in[14]; P.ab3 = (const float*)d_in[15];
    P.pw1 = (const float*)d_in[16]; P.pb1 = (const float*)d_in[17];
    P.pw2 = (const float*)d_in[18]; P.pb2 = (const float*)d_in[19];
    P.pw3 = (const float*)d_in[20]; P.pb3 = (const float*)d_in[21];

    char* ws = (char*)d_ws;
    P.flags = (int*)ws;                              // 9 ints, zeroed below
    P.l2c   = (float*)(ws + 256);                    // [8][28][128]
    P.h2a   = P.l2c + NBATCH * 28 * CCH;             // [8][128]
    P.out   = (float*)d_out;

    hipMemsetAsync(d_ws, 0, 256, stream);            // flags must start at 0
    k_fused<<<dim3(288), dim3(512), 0, stream>>>(P);
}

// Round 13
// 54.838 us; speedup vs baseline: 1.3516x; 1.3516x over previous
//
#include <hip/hip_runtime.h>

#define CCH 128      // channels
#define TLEN 2048
#define NBATCH 8
#define NATOMS 3584
#define NEG 0.2f
typedef unsigned long long ull;

// 7-bit packed index lists (up to 9 slots)
#define PK1(a) ((ull)(a))
#define PK2(a,b) (PK1(a)|((ull)(b)<<7))
#define PK3(a,b,c) (PK2(a,b)|((ull)(c)<<14))
#define PK4(a,b,c,d) (PK3(a,b,c)|((ull)(d)<<21))
// 6-bit packed (10 slots in 60 bits)
#define P6(v,k) ((ull)(v)<<(6*(k)))
#define PX10(a,b,c,d,e,f,g,h,i,j) (P6(a,0)|P6(b,1)|P6(c,2)|P6(d,3)|P6(e,4)| \
    P6(f,5)|P6(g,6)|P6(h,7)|P6(i,8)|P6(j,9))

// Per-batch unique L2 columns (union of {o-9,o,o+9} for L3 cols
// o in {18,19,45,46,72,73,99,100,126,127}), sorted:
__device__ const int g_l2cols[28] = {
    9,10,18,19,27,28,36,37,45,46,54,55,63,64,
    72,73,81,82,90,91,99,100,108,109,117,118,126,127};

__device__ __forceinline__ float lrelu(float v) { return v >= 0.f ? v : NEG * v; }
__device__ __forceinline__ float dot4(float4 w, float4 x) {
    return w.x * x.x + w.y * x.y + w.z * x.z + w.w * x.w;
}

// Touch weights to warm caches (keep-alive defeats DCE, rule #17).
__device__ __forceinline__ void warm(const float* p, int nf4, int gid, int nthr) {
    const float4* q = (const float4*)p;
    for (int i = gid; i < nf4; i += nthr) {
        float4 v = q[i];
        asm volatile("" :: "v"(v.x), "v"(v.y), "v"(v.z), "v"(v.w));
    }
}

// Reduce 4 accumulators over the 16 K-split lanes (tid = g*16+s).
__device__ __forceinline__ float red16x4(float a0, float a1, float a2, float a3, int s) {
    a0 += __shfl_xor(a0, 8); a1 += __shfl_xor(a1, 8);
    a2 += __shfl_xor(a2, 8); a3 += __shfl_xor(a3, 8);
    a0 += __shfl_xor(a0, 4); a1 += __shfl_xor(a1, 4);
    a2 += __shfl_xor(a2, 4); a3 += __shfl_xor(a3, 4);
    float u0 = (s & 2) ? a2 : a0;
    float v0 = (s & 2) ? a0 : a2;
    u0 += __shfl_xor(v0, 2);
    float u1 = (s & 2) ? a3 : a1;
    float v1 = (s & 2) ? a1 : a3;
    u1 += __shfl_xor(v1, 2);
    float w  = (s & 1) ? u1 : u0;
    float vv = (s & 1) ? u0 : u1;
    w += __shfl_xor(vv, 1);
    return w;
}

// One residual dilated block over NB scratch columns (see R7-R10 comments).
template<int NB, int SH = 7>
__device__ __forceinline__ void conv4(
        const float (*src)[CCH], float (*dst)[CCH], float* gout,
        ull pm, ull pc, ull pp, ull pd, int a0,
        const float* __restrict__ Wd, const float* __restrict__ bd,
        const float* __restrict__ Wo, const float* __restrict__ bo,
        float (*ybuf)[CCH], int g, int s)
{
    const int MSK = (1 << SH) - 1;
    const int ch = 4 * g + (s & 3);
    const float myBd = bd[ch];
    const float myBo = bo[ch];
    float4 W[24], V[8];
    {
        const float4* Wr = (const float4*)Wd + (size_t)(4 * g) * 96;
        #pragma unroll
        for (int r = 0; r < 4; ++r)
            #pragma unroll
            for (int j = 0; j < 3; ++j) {
                W[r * 6 + j]     = Wr[r * 96 + 3 * s + j];
                W[r * 6 + 3 + j] = Wr[r * 96 + 3 * s + 48 + j];
            }
        const float4* Or = (const float4*)Wo + (size_t)(4 * g) * 32;
        #pragma unroll
        for (int r = 0; r < 4; ++r) {
            V[r * 2]     = Or[r * 32 + s];
            V[r * 2 + 1] = Or[r * 32 + s + 16];
        }
    }
    __syncthreads();                     // src ready + ybuf free
    #pragma unroll
    for (int t = 0; t < NB; ++t) {
        const float* fm = src[(int)((pm >> (SH * t)) & MSK)];
        const float* fc = src[(int)((pc >> (SH * t)) & MSK)];
        const float* fp = src[(int)((pp >> (SH * t)) & MSK)];
        float4 m0 = *(const float4*)(fm + 4 * s);
        float4 m1 = *(const float4*)(fm + 4 * s + 64);
        float4 c0 = *(const float4*)(fc + 4 * s);
        float4 c1 = *(const float4*)(fc + 4 * s + 64);
        float4 p0 = *(const float4*)(fp + 4 * s);
        float4 p1 = *(const float4*)(fp + 4 * s + 64);
        float acc[4];
        #pragma unroll
        for (int r = 0; r < 4; ++r) {
            float4 wA = W[r*6+0], wB = W[r*6+1], wC = W[r*6+2];
            float a = wA.x*m0.x + wA.y*c0.x + wA.z*p0.x + wA.w*m0.y
                    + wB.x*c0.y + wB.y*p0.y + wB.z*m0.z + wB.w*c0.z
                    + wC.x*p0.z + wC.y*m0.w + wC.z*c0.w + wC.w*p0.w;
            float4 wD = W[r*6+3], wE = W[r*6+4], wF = W[r*6+5];
            float b2 = wD.x*m1.x + wD.y*c1.x + wD.z*p1.x + wD.w*m1.y
                     + wE.x*c1.y + wE.y*p1.y + wE.z*m1.z + wE.w*c1.z
                     + wF.x*p1.z + wF.y*m1.w + wF.z*c1.w + wF.w*p1.w;
            acc[r] = a + b2;
        }
        float tot = red16x4(acc[0], acc[1], acc[2], acc[3], s);
        if (s < 4) ybuf[t][ch] = tot + myBd;
    }
    __syncthreads();                     // ybuf ready
    #pragma unroll
    for (int t = 0; t < NB; ++t) {
        int jc = (int)((pc >> (SH * t)) & MSK);
        int jd = (int)((pd >> (SH * t)) & MSK);
        const float* y = ybuf[t];
        float4 y0 = *(const float4*)(y + 4 * s);
        float4 y1 = *(const float4*)(y + 4 * s + 64);
        float a0_ = dot4(V[0], y0) + dot4(V[1], y1);
        float a1_ = dot4(V[2], y0) + dot4(V[3], y1);
        float a2_ = dot4(V[4], y0) + dot4(V[5], y1);
        float a3_ = dot4(V[6], y0) + dot4(V[7], y1);
        float tot = red16x4(a0_, a1_, a2_, a3_, s);
        if (s < 4) {
            float h = lrelu(tot + myBo + src[jc][ch]);
            if (gout) gout[ch] = h;
            else      dst[jd][ch] = (a0 + jd < 128) ? h : 0.f;
        }
    }
}

// K=128 matvec stage (MLP hidden layer), R=4/S=16 mapping, lrelu.
__device__ __forceinline__ void mlp4(
        const float* hin, float* hout,
        const float* __restrict__ w, const float* __restrict__ bv,
        int g, int s)
{
    const int ch = 4 * g + (s & 3);
    const float myB = bv[ch];
    float4 V[8];
    const float4* r = (const float4*)w + (size_t)(4 * g) * 32;
    #pragma unroll
    for (int rr = 0; rr < 4; ++rr) {
        V[rr * 2]     = r[rr * 32 + s];
        V[rr * 2 + 1] = r[rr * 32 + s + 16];
    }
    __syncthreads();                     // hin ready
    float4 x0 = *(const float4*)(hin + 4 * s);
    float4 x1 = *(const float4*)(hin + 4 * s + 64);
    float a0_ = dot4(V[0], x0) + dot4(V[1], x1);
    float a1_ = dot4(V[2], x0) + dot4(V[3], x1);
    float a2_ = dot4(V[4], x0) + dot4(V[5], x1);
    float a3_ = dot4(V[6], x0) + dot4(V[7], x1);
    float tot = red16x4(a0_, a1_, a2_, a3_, s);
    if (s < 4) hout[ch] = lrelu(tot + myB);
}

// ---------------------------------------------------------------------------
// K1: mini-cone for one L2 column (R10-verbatim). grid (28, 8).
// own = g_l2cols[i]; scratch j: abs = a0 + j, a0 = own-4. setup j in [0,9);
// L1 (d=1) dst {1,4,7}; L2 (d=3) dst {4} -> l2c[b][i][:]. Exact.
// Warms all downstream weights into L3 (harness fills flush caches/replay).
// ---------------------------------------------------------------------------
__global__ void __launch_bounds__(512, 2) k_cone(
        const float* __restrict__ x,
        const float* __restrict__ embed_w,
        const float* __restrict__ posamp_w,
        const float* __restrict__ posamp_b,
        const float* __restrict__ reduce_w,
        const float* __restrict__ reduce_b,
        const float* __restrict__ dil_w,
        const float* __restrict__ dil_b,
        const float* __restrict__ one_w,
        const float* __restrict__ one_b,
        const float* __restrict__ aw1, const float* __restrict__ aw2,
        const float* __restrict__ pw1, const float* __restrict__ pw2,
        const float* __restrict__ aw3,
        float* __restrict__ l2c)
{
    const int i   = blockIdx.x;
    const int b   = blockIdx.y;
    const int own = g_l2cols[i];
    const int a0  = own - 4;
    const int tid = threadIdx.x;
    const int g   = tid >> 4;
    const int s   = tid & 15;
    const int ch  = 4 * g + (s & 3);

    // ---- prefetch downstream weights into L3 (parallel across 224 blocks) ----
    {
        const int gid  = (b * 28 + i) * 512 + tid;
        const int nthr = 224 * 512;
        warm(dil_w + (size_t)2 * CCH * CCH * 3, 4 * CCH * CCH * 3 / 4, gid, nthr);
        warm(one_w + (size_t)2 * CCH * CCH,     4 * CCH * CCH / 4,     gid, nthr);
        warm(aw1, CCH * CCH / 4, gid, nthr);
        warm(aw2, CCH * CCH / 4, gid, nthr);
        warm(pw1, CCH * CCH / 4, gid, nthr);
        warm(pw2, CCH * CCH / 4, gid, nthr);
        warm(aw3, NATOMS * CCH / 4, gid, nthr);
    }

    __shared__ float A[9][CCH];            // setup
    __shared__ float B[8][CCH];            // L1 dst {1,4,7}
    __shared__ float cat[9][2 * CCH];      // 9.2 KB
    __shared__ float ybuf[3][CCH];

    // ---- fill concat for 9 cols ----
    const float* xb = x + b * 4 * TLEN;
    for (int v = tid; v < 9 * 256; v += 512) {
        int p   = v >> 8;
        int chv = v & 255;
        int ab  = a0 + p;
        float val = 0.f;
        if (ab < 128) {
            int t = (TLEN - 128) + ab;
            if (chv < CCH) {
                int idx = (int)xb[t];            // atom id (exact int in f32)
                val = embed_w[idx * CCH + chv];
            } else {
                int cc = chv - CCH;
                val = posamp_w[2 * cc] * xb[TLEN + t]
                    + posamp_w[2 * cc + 1] * xb[2 * TLEN + t] + posamp_b[cc];
            }
        }
        cat[p][chv] = val;
    }
    // setup weights: rows 4g..4g+3, chunks {s, s+16, s+32, s+48}
    float4 RW[16];
    const float4* rw = (const float4*)reduce_w + (size_t)(4 * g) * 64;
    #pragma unroll
    for (int r = 0; r < 4; ++r)
        #pragma unroll
        for (int j = 0; j < 4; ++j)
            RW[r * 4 + j] = rw[r * 64 + s + 16 * j];
    const float rb = reduce_b[ch];
    __syncthreads();

    // ---- setup reduce: A[t] for t in [0,9) ----
    #pragma unroll 3
    for (int t = 0; t < 9; ++t) {
        const float* sc = cat[t];
        float4 x0 = *(const float4*)(sc + 4 * s);
        float4 x1 = *(const float4*)(sc + 4 * s + 64);
        float4 x2 = *(const float4*)(sc + 4 * s + 128);
        float4 x3 = *(const float4*)(sc + 4 * s + 192);
        float a0_ = dot4(RW[0], x0) + dot4(RW[1], x1) + dot4(RW[2], x2) + dot4(RW[3], x3);
        float a1_ = dot4(RW[4], x0) + dot4(RW[5], x1) + dot4(RW[6], x2) + dot4(RW[7], x3);
        float a2_ = dot4(RW[8], x0) + dot4(RW[9], x1) + dot4(RW[10], x2) + dot4(RW[11], x3);
        float a3_ = dot4(RW[12], x0) + dot4(RW[13], x1) + dot4(RW[14], x2) + dot4(RW[15], x3);
        float tot = red16x4(a0_, a1_, a2_, a3_, s);
        if (s < 4) A[t][ch] = (a0 + t < 128) ? tot + rb : 0.f;
    }

    // ---- L1 (d=1): A -> B, dst {1,4,7} ----
    conv4<3>(A, B, nullptr,
             PK3(0,3,6), PK3(1,4,7), PK3(2,5,8), PK3(1,4,7), a0,
             dil_w, dil_b, one_w, one_b, ybuf, g, s);
    // ---- L2 (d=3): B -> global l2c[b][i] ----
    conv4<1>(B, B, l2c + (size_t)(b * 28 + i) * CCH,
             PK1(1), PK1(4), PK1(7), PK1(4), a0,
             dil_w + (size_t)1 * CCH * CCH * 3, dil_b + CCH,
             one_w + (size_t)1 * CCH * CCH, one_b + CCH, ybuf, g, s);
}

// ---------------------------------------------------------------------------
// K2: per-batch tail, 8 blocks (tail weights read 8x aggregate, not 64x).
// Stage 28 L2 cols -> L3 (conv4<10,6>) -> L4 -> L5 -> L6 -> MLPs ->
// h2a[b] to ws + pa head to out.
// ---------------------------------------------------------------------------
__global__ void __launch_bounds__(512, 2) k_tail(
        const float* __restrict__ l2c,
        const float* __restrict__ dil_w,
        const float* __restrict__ dil_b,
        const float* __restrict__ one_w,
        const float* __restrict__ one_b,
        const float* __restrict__ aw1, const float* __restrict__ ab1,
        const float* __restrict__ aw2, const float* __restrict__ ab2,
        const float* __restrict__ pw1, const float* __restrict__ pb1,
        const float* __restrict__ pw2, const float* __restrict__ pb2,
        const float* __restrict__ pw3, const float* __restrict__ pb3,
        float* __restrict__ h2w,
        float* __restrict__ out)
{
    const int b   = blockIdx.x;
    const int tid = threadIdx.x;
    const int g   = tid >> 4;
    const int s   = tid & 15;

    __shared__ float E[29][CCH];           // 28 L2 cols + Z
    __shared__ float D[11][CCH];           // 10 L3 cols + Z
    __shared__ float B2[5][CCH];           // L4 {45,46,126,127} + Z
    __shared__ float C2[3][CCH];           // L5 {126,127} + Z
    __shared__ float HF[CCH];              // L6 {127}
    __shared__ float ybuf[10][CCH];
    __shared__ float h1a[CCH], h1p[CCH], h2p[CCH];

    if (tid < CCH) { E[28][tid] = 0.f; D[10][tid] = 0.f; B2[4][tid] = 0.f; C2[2][tid] = 0.f; }
    for (int v = tid; v < 28 * 32; v += 512) {
        int col = v >> 5, f4i = v & 31;
        *(float4*)&E[col][f4i * 4] =
            *(const float4*)(l2c + (size_t)(b * 28 + col) * CCH + f4i * 4);
    }

    // L3 (d=9), all 10 cols in one weight phase (6-bit packing)
    conv4<10, 6>(E, D, nullptr,
             PX10(0,1,6,7,12,13,18,19,24,25),
             PX10(2,3,8,9,14,15,20,21,26,27),
             PX10(4,5,10,11,16,17,22,23,28,28),
             PX10(0,1,2,3,4,5,6,7,8,9), -1000,
             dil_w + (size_t)2 * CCH * CCH * 3, dil_b + 2 * CCH,
             one_w + (size_t)2 * CCH * CCH, one_b + 2 * CCH, ybuf, g, s);
    // L4: 45:{18,45,72} 46:{19,46,73} 126:{99,126,Z} 127:{100,127,Z}
    conv4<4>(D, B2, nullptr,
             PK4(0,1,6,7), PK4(2,3,8,9), PK4(4,5,10,10), PK4(0,1,2,3), -1000,
             dil_w + (size_t)3 * CCH * CCH * 3, dil_b + 3 * CCH,
             one_w + (size_t)3 * CCH * CCH, one_b + 3 * CCH, ybuf, g, s);
    // L5: 126:{45,126,Z} 127:{46,127,Z}
    conv4<2>(B2, C2, nullptr,
             PK2(0,1), PK2(2,3), PK2(4,4), PK2(0,1), -1000,
             dil_w + (size_t)4 * CCH * CCH * 3, dil_b + 4 * CCH,
             one_w + (size_t)4 * CCH * CCH, one_b + 4 * CCH, ybuf, g, s);
    // L6: 127:{126,127,Z} -> HF
    conv4<1>(C2, C2, HF,
             PK1(0), PK1(1), PK1(2), PK1(0), -1000,
             dil_w + (size_t)5 * CCH * CCH * 3, dil_b + 5 * CCH,
             one_w + (size_t)5 * CCH * CCH, one_b + 5 * CCH, ybuf, g, s);

    // ---- MLP hidden layers ----
    mlp4(HF,  h1a, aw1, ab1, g, s);
    mlp4(HF,  h1p, pw1, pb1, g, s);
    mlp4(h1a, h2w + b * CCH, aw2, ab2, g, s);   // atom h2 -> global ws
    mlp4(h1p, h2p, pw2, pb2, g, s);
    __syncthreads();

    // ---- pa head: 2 outputs, K=128 over 64 lanes ----
    if (tid < 64) {
        int row = tid >> 5, q = tid & 31;
        float4 w4 = *(const float4*)(pw3 + row * CCH + 4 * q);
        float4 xv = *(const float4*)(h2p + 4 * q);
        float acc = dot4(w4, xv);
        acc += __shfl_xor(acc, 1);
        acc += __shfl_xor(acc, 2);
        acc += __shfl_xor(acc, 4);
        acc += __shfl_xor(acc, 8);
        acc += __shfl_xor(acc, 16);
        if (q == 0) out[NBATCH * NATOMS + b * 2 + row] = acc + pb3[row];
    }
}

// ---------------------------------------------------------------------------
// K3: atom logits, aw3 read ONCE aggregate. 56 blocks; block j owns rows
// [64j, 64j+64) and computes them for ALL 8 batches (h2a 4 KB in LDS).
// ---------------------------------------------------------------------------
__global__ void __launch_bounds__(512, 2) k_head(
        const float* __restrict__ h2w,
        const float* __restrict__ aw3, const float* __restrict__ ab3,
        float* __restrict__ out)
{
    const int j   = blockIdx.x;
    const int tid = threadIdx.x;

    __shared__ float hs[NBATCH][CCH];      // 4 KB
    if (tid < 256)
        ((float4*)hs)[tid] = ((const float4*)h2w)[tid];
    __syncthreads();

    const int b   = tid >> 6;              // wave-uniform batch
    const int r   = tid & 63;
    const int row = j * 64 + r;
    const float4* wr = (const float4*)(aw3 + (size_t)row * CCH);
    const float*  h  = hs[b];              // wave-uniform LDS broadcasts
    float s0 = 0.f, s1 = 0.f, s2 = 0.f, s3 = 0.f;
    #pragma unroll
    for (int k = 0; k < 32; k += 4) {
        s0 += dot4(wr[k],     *(const float4*)&h[4 * k]);
        s1 += dot4(wr[k + 1], *(const float4*)&h[4 * k + 4]);
        s2 += dot4(wr[k + 2], *(const float4*)&h[4 * k + 8]);
        s3 += dot4(wr[k + 3], *(const float4*)&h[4 * k + 12]);
    }
    out[b * NATOMS + row] = s0 + s1 + s2 + s3 + ab3[row];
}

// ---------------------------------------------------------------------------
extern "C" void kernel_launch(void* const* d_in, const int* in_sizes, int n_in,
                              void* d_out, int out_size, void* d_ws, size_t ws_size,
                              hipStream_t stream)
{
    const float* x        = (const float*)d_in[0];
    const float* embed_w  = (const float*)d_in[1];
    const float* posamp_w = (const float*)d_in[2];
    const float* posamp_b = (const float*)d_in[3];
    const float* reduce_w = (const float*)d_in[4];
    const float* reduce_b = (const float*)d_in[5];
    const float* dil_w    = (const float*)d_in[6];
    const float* dil_b    = (const float*)d_in[7];
    const float* one_w    = (const float*)d_in[8];
    const float* one_b    = (const float*)d_in[9];
    const float* aw1 = (const float*)d_in[10]; const float* ab1 = (const float*)d_in[11];
    const float* aw2 = (const float*)d_in[12]; const float* ab2 = (const float*)d_in[13];
    const float* aw3 = (const float*)d_in[14]; const float* ab3 = (const float*)d_in[15];
    const float* pw1 = (const float*)d_in[16]; const float* pb1 = (const float*)d_in[17];
    const float* pw2 = (const float*)d_in[18]; const float* pb2 = (const float*)d_in[19];
    const float* pw3 = (const float*)d_in[20]; const float* pb3 = (const float*)d_in[21];

    float* l2c = (float*)d_ws;                 // [8][28][128] = 114 KB
    float* h2w = l2c + NBATCH * 28 * CCH;      // [8][128]

    k_cone<<<dim3(28, NBATCH), dim3(512), 0, stream>>>(
        x, embed_w, posamp_w, posamp_b, reduce_w, reduce_b,
        dil_w, dil_b, one_w, one_b,
        aw1, aw2, pw1, pw2, aw3, l2c);

    k_tail<<<dim3(NBATCH), dim3(512), 0, stream>>>(
        l2c, dil_w, dil_b, one_w, one_b,
        aw1, ab1, aw2, ab2, pw1, pb1, pw2, pb2, pw3, pb3,
        h2w, (float*)d_out);

    k_head<<<dim3(56), dim3(512), 0, stream>>>(
        h2w, aw3, ab3, (float*)d_out);
}

// Round 14
// 51.809 us; speedup vs baseline: 1.4306x; 1.0585x over previous
//
#include <hip/hip_runtime.h>

#define CCH 128      // channels
#define TLEN 2048
#define NBATCH 8
#define NATOMS 3584
#define NEG 0.2f
typedef unsigned long long ull;

// 7-bit packed index lists (up to 9 slots)
#define PK1(a) ((ull)(a))
#define PK2(a,b) (PK1(a)|((ull)(b)<<7))
#define PK3(a,b,c) (PK2(a,b)|((ull)(c)<<14))
#define PK4(a,b,c,d) (PK3(a,b,c)|((ull)(d)<<21))
// 6-bit packed (10 slots in 60 bits)
#define P6(v,k) ((ull)(v)<<(6*(k)))
#define PX10(a,b,c,d,e,f,g,h,i,j) (P6(a,0)|P6(b,1)|P6(c,2)|P6(d,3)|P6(e,4)| \
    P6(f,5)|P6(g,6)|P6(h,7)|P6(i,8)|P6(j,9))

// Per-batch unique L2 columns (union of {o-9,o,o+9} for L3 cols
// o in {18,19,45,46,72,73,99,100,126,127}), sorted:
__device__ const int g_l2cols[28] = {
    9,10,18,19,27,28,36,37,45,46,54,55,63,64,
    72,73,81,82,90,91,99,100,108,109,117,118,126,127};

__device__ __forceinline__ float lrelu(float v) { return v >= 0.f ? v : NEG * v; }
__device__ __forceinline__ float dot4(float4 w, float4 x) {
    return w.x * x.x + w.y * x.y + w.z * x.z + w.w * x.w;
}

// Touch weights to warm L3 (keep-alive defeats DCE, rule #17).
__device__ __forceinline__ void warm(const float* p, int nf4, int gid, int nthr) {
    const float4* q = (const float4*)p;
    for (int i = gid; i < nf4; i += nthr) {
        float4 v = q[i];
        asm volatile("" :: "v"(v.x), "v"(v.y), "v"(v.z), "v"(v.w));
    }
}

// Reduce 4 accumulators over the 16 K-split lanes (tid = g*16+s).
// Returns the full sum of acc_{s&3}; lane s holds out-ch 4g + (s&3).
__device__ __forceinline__ float red16x4(float a0, float a1, float a2, float a3, int s) {
    a0 += __shfl_xor(a0, 8); a1 += __shfl_xor(a1, 8);
    a2 += __shfl_xor(a2, 8); a3 += __shfl_xor(a3, 8);
    a0 += __shfl_xor(a0, 4); a1 += __shfl_xor(a1, 4);
    a2 += __shfl_xor(a2, 4); a3 += __shfl_xor(a3, 4);
    float u0 = (s & 2) ? a2 : a0;
    float v0 = (s & 2) ? a0 : a2;
    u0 += __shfl_xor(v0, 2);
    float u1 = (s & 2) ? a3 : a1;
    float v1 = (s & 2) ? a1 : a3;
    u1 += __shfl_xor(v1, 2);
    float w  = (s & 1) ? u1 : u0;
    float vv = (s & 1) ? u0 : u1;
    w += __shfl_xor(vv, 1);
    return w;
}

// One residual dilated block over NB (compile-time) scratch columns.
// R=4 out-ch/thread (rows 4g..4g+3), S=16 K-split: lane s owns in-ch chunks
// {4s..4s+3, 64+4s..64+4s+3} (strided -> conflict-free LDS banks).
// pm/pc/pp/pd: packed (SH bits/slot) src(-d), src(0)=residual, src(+d), dst.
// dst col forced 0 when a0+jd >= 128; gout!=null (NB==1): write gout[ch].
template<int NB, int SH = 7>
__device__ __forceinline__ void conv4(
        const float (*src)[CCH], float (*dst)[CCH], float* gout,
        ull pm, ull pc, ull pp, ull pd, int a0,
        const float* __restrict__ Wd, const float* __restrict__ bd,
        const float* __restrict__ Wo, const float* __restrict__ bo,
        float (*ybuf)[CCH], int g, int s)
{
    const int MSK = (1 << SH) - 1;
    const int ch = 4 * g + (s & 3);
    const float myBd = bd[ch];
    const float myBo = bo[ch];
    float4 W[24], V[8];
    {
        const float4* Wr = (const float4*)Wd + (size_t)(4 * g) * 96;
        #pragma unroll
        for (int r = 0; r < 4; ++r)
            #pragma unroll
            for (int j = 0; j < 3; ++j) {
                W[r * 6 + j]     = Wr[r * 96 + 3 * s + j];
                W[r * 6 + 3 + j] = Wr[r * 96 + 3 * s + 48 + j];
            }
        const float4* Or = (const float4*)Wo + (size_t)(4 * g) * 32;
        #pragma unroll
        for (int r = 0; r < 4; ++r) {
            V[r * 2]     = Or[r * 32 + s];
            V[r * 2 + 1] = Or[r * 32 + s + 16];
        }
    }
    __syncthreads();                     // src ready + ybuf free
    #pragma unroll
    for (int t = 0; t < NB; ++t) {
        const float* fm = src[(int)((pm >> (SH * t)) & MSK)];
        const float* fc = src[(int)((pc >> (SH * t)) & MSK)];
        const float* fp = src[(int)((pp >> (SH * t)) & MSK)];
        float4 m0 = *(const float4*)(fm + 4 * s);
        float4 m1 = *(const float4*)(fm + 4 * s + 64);
        float4 c0 = *(const float4*)(fc + 4 * s);
        float4 c1 = *(const float4*)(fc + 4 * s + 64);
        float4 p0 = *(const float4*)(fp + 4 * s);
        float4 p1 = *(const float4*)(fp + 4 * s + 64);
        float acc[4];
        #pragma unroll
        for (int r = 0; r < 4; ++r) {
            float4 wA = W[r*6+0], wB = W[r*6+1], wC = W[r*6+2];
            float a = wA.x*m0.x + wA.y*c0.x + wA.z*p0.x + wA.w*m0.y
                    + wB.x*c0.y + wB.y*p0.y + wB.z*m0.z + wB.w*c0.z
                    + wC.x*p0.z + wC.y*m0.w + wC.z*c0.w + wC.w*p0.w;
            float4 wD = W[r*6+3], wE = W[r*6+4], wF = W[r*6+5];
            float b2 = wD.x*m1.x + wD.y*c1.x + wD.z*p1.x + wD.w*m1.y
                     + wE.x*c1.y + wE.y*p1.y + wE.z*m1.z + wE.w*c1.z
                     + wF.x*p1.z + wF.y*m1.w + wF.z*c1.w + wF.w*p1.w;
            acc[r] = a + b2;
        }
        float tot = red16x4(acc[0], acc[1], acc[2], acc[3], s);
        if (s < 4) ybuf[t][ch] = tot + myBd;
    }
    __syncthreads();                     // ybuf ready
    #pragma unroll
    for (int t = 0; t < NB; ++t) {
        int jc = (int)((pc >> (SH * t)) & MSK);
        int jd = (int)((pd >> (SH * t)) & MSK);
        const float* y = ybuf[t];
        float4 y0 = *(const float4*)(y + 4 * s);
        float4 y1 = *(const float4*)(y + 4 * s + 64);
        float a0_ = dot4(V[0], y0) + dot4(V[1], y1);
        float a1_ = dot4(V[2], y0) + dot4(V[3], y1);
        float a2_ = dot4(V[4], y0) + dot4(V[5], y1);
        float a3_ = dot4(V[6], y0) + dot4(V[7], y1);
        float tot = red16x4(a0_, a1_, a2_, a3_, s);
        if (s < 4) {
            float h = lrelu(tot + myBo + src[jc][ch]);
            if (gout) gout[ch] = h;
            else      dst[jd][ch] = (a0 + jd < 128) ? h : 0.f;
        }
    }
}

// Dual K=128 matvec: two 128-row matvecs (atom & pa) in ONE weight phase.
// S=8 K-split: lane s8 = tid&7 owns float4 chunks at 4*s8 + 32j (j=0..3).
// g64 = tid>>3 in [0,64): g64<32 -> atom rows 4*g64.., else pa rows 4*(g64-32).
__device__ __forceinline__ void mlp4dual(
        const float* hinA, const float* hinP,
        float* houtA, float* houtP,
        const float* __restrict__ wa, const float* __restrict__ ba,
        const float* __restrict__ wp, const float* __restrict__ bp,
        int tid)
{
    const int s8  = tid & 7;
    const int g64 = tid >> 3;
    const int sel = g64 >> 5;            // 0: atom, 1: pa
    const int gi  = g64 & 31;
    const int ch  = 4 * gi + (s8 & 3);
    const float* w   = sel ? wp : wa;
    const float myB  = (sel ? bp : ba)[ch];
    const float* hin = sel ? hinP : hinA;
    float* hout      = sel ? houtP : houtA;
    float4 V[16];
    const float4* r = (const float4*)w + (size_t)(4 * gi) * 32;
    #pragma unroll
    for (int rr = 0; rr < 4; ++rr)
        #pragma unroll
        for (int j = 0; j < 4; ++j)
            V[rr * 4 + j] = r[rr * 32 + s8 + 8 * j];
    __syncthreads();                     // hin ready
    float4 x0 = *(const float4*)(hin + 4 * s8);
    float4 x1 = *(const float4*)(hin + 4 * s8 + 32);
    float4 x2 = *(const float4*)(hin + 4 * s8 + 64);
    float4 x3 = *(const float4*)(hin + 4 * s8 + 96);
    float a0 = dot4(V[0],x0)+dot4(V[1],x1)+dot4(V[2],x2)+dot4(V[3],x3);
    float a1 = dot4(V[4],x0)+dot4(V[5],x1)+dot4(V[6],x2)+dot4(V[7],x3);
    float a2 = dot4(V[8],x0)+dot4(V[9],x1)+dot4(V[10],x2)+dot4(V[11],x3);
    float a3 = dot4(V[12],x0)+dot4(V[13],x1)+dot4(V[14],x2)+dot4(V[15],x3);
    a0 += __shfl_xor(a0, 4); a1 += __shfl_xor(a1, 4);
    a2 += __shfl_xor(a2, 4); a3 += __shfl_xor(a3, 4);
    float u0 = (s8 & 2) ? a2 : a0;
    float v0 = (s8 & 2) ? a0 : a2;
    u0 += __shfl_xor(v0, 2);
    float u1 = (s8 & 2) ? a3 : a1;
    float v1 = (s8 & 2) ? a1 : a3;
    u1 += __shfl_xor(v1, 2);
    float wv = (s8 & 1) ? u1 : u0;
    float vv = (s8 & 1) ? u0 : u1;
    wv += __shfl_xor(vv, 1);
    if (s8 < 4) hout[ch] = lrelu(wv + myB);
}

// ---------------------------------------------------------------------------
// K1: mini-cone for one L2 column (R10-verbatim). grid (28, 8).
// own = g_l2cols[i]; scratch j: abs = a0 + j, a0 = own-4. setup j in [0,9);
// L1 (d=1) dst {1,4,7}; L2 (d=3) dst {4} -> l2c[b][i][:]. Exact.
// Warms all downstream weights into L3 (harness fills flush caches/replay).
// ---------------------------------------------------------------------------
__global__ void __launch_bounds__(512, 2) k_cone(
        const float* __restrict__ x,
        const float* __restrict__ embed_w,
        const float* __restrict__ posamp_w,
        const float* __restrict__ posamp_b,
        const float* __restrict__ reduce_w,
        const float* __restrict__ reduce_b,
        const float* __restrict__ dil_w,
        const float* __restrict__ dil_b,
        const float* __restrict__ one_w,
        const float* __restrict__ one_b,
        const float* __restrict__ aw1, const float* __restrict__ aw2,
        const float* __restrict__ pw1, const float* __restrict__ pw2,
        const float* __restrict__ aw3,
        float* __restrict__ l2c)
{
    const int i   = blockIdx.x;
    const int b   = blockIdx.y;
    const int own = g_l2cols[i];
    const int a0  = own - 4;
    const int tid = threadIdx.x;
    const int g   = tid >> 4;
    const int s   = tid & 15;
    const int ch  = 4 * g + (s & 3);

    // ---- prefetch downstream weights into L3 (parallel across 224 blocks) ----
    {
        const int gid  = (b * 28 + i) * 512 + tid;
        const int nthr = 224 * 512;
        warm(dil_w + (size_t)2 * CCH * CCH * 3, 4 * CCH * CCH * 3 / 4, gid, nthr);
        warm(one_w + (size_t)2 * CCH * CCH,     4 * CCH * CCH / 4,     gid, nthr);
        warm(aw1, CCH * CCH / 4, gid, nthr);
        warm(aw2, CCH * CCH / 4, gid, nthr);
        warm(pw1, CCH * CCH / 4, gid, nthr);
        warm(pw2, CCH * CCH / 4, gid, nthr);
        warm(aw3, NATOMS * CCH / 4, gid, nthr);
    }

    __shared__ float A[9][CCH];            // setup
    __shared__ float B[8][CCH];            // L1 dst {1,4,7}
    __shared__ float cat[9][2 * CCH];      // 9.2 KB
    __shared__ float ybuf[3][CCH];

    // ---- fill concat for 9 cols ----
    const float* xb = x + b * 4 * TLEN;
    for (int v = tid; v < 9 * 256; v += 512) {
        int p   = v >> 8;
        int chv = v & 255;
        int ab  = a0 + p;
        float val = 0.f;
        if (ab < 128) {
            int t = (TLEN - 128) + ab;
            if (chv < CCH) {
                int idx = (int)xb[t];            // atom id (exact int in f32)
                val = embed_w[idx * CCH + chv];
            } else {
                int cc = chv - CCH;
                val = posamp_w[2 * cc] * xb[TLEN + t]
                    + posamp_w[2 * cc + 1] * xb[2 * TLEN + t] + posamp_b[cc];
            }
        }
        cat[p][chv] = val;
    }
    // setup weights: rows 4g..4g+3, chunks {s, s+16, s+32, s+48}
    float4 RW[16];
    const float4* rw = (const float4*)reduce_w + (size_t)(4 * g) * 64;
    #pragma unroll
    for (int r = 0; r < 4; ++r)
        #pragma unroll
        for (int j = 0; j < 4; ++j)
            RW[r * 4 + j] = rw[r * 64 + s + 16 * j];
    const float rb = reduce_b[ch];
    __syncthreads();

    // ---- setup reduce: A[t] for t in [0,9) ----
    #pragma unroll 3
    for (int t = 0; t < 9; ++t) {
        const float* sc = cat[t];
        float4 x0 = *(const float4*)(sc + 4 * s);
        float4 x1 = *(const float4*)(sc + 4 * s + 64);
        float4 x2 = *(const float4*)(sc + 4 * s + 128);
        float4 x3 = *(const float4*)(sc + 4 * s + 192);
        float a0_ = dot4(RW[0], x0) + dot4(RW[1], x1) + dot4(RW[2], x2) + dot4(RW[3], x3);
        float a1_ = dot4(RW[4], x0) + dot4(RW[5], x1) + dot4(RW[6], x2) + dot4(RW[7], x3);
        float a2_ = dot4(RW[8], x0) + dot4(RW[9], x1) + dot4(RW[10], x2) + dot4(RW[11], x3);
        float a3_ = dot4(RW[12], x0) + dot4(RW[13], x1) + dot4(RW[14], x2) + dot4(RW[15], x3);
        float tot = red16x4(a0_, a1_, a2_, a3_, s);
        if (s < 4) A[t][ch] = (a0 + t < 128) ? tot + rb : 0.f;
    }

    // ---- L1 (d=1): A -> B, dst {1,4,7} ----
    conv4<3>(A, B, nullptr,
             PK3(0,3,6), PK3(1,4,7), PK3(2,5,8), PK3(1,4,7), a0,
             dil_w, dil_b, one_w, one_b, ybuf, g, s);
    // ---- L2 (d=3): B -> global l2c[b][i] ----
    conv4<1>(B, B, l2c + (size_t)(b * 28 + i) * CCH,
             PK1(1), PK1(4), PK1(7), PK1(4), a0,
             dil_w + (size_t)1 * CCH * CCH * 3, dil_b + CCH,
             one_w + (size_t)1 * CCH * CCH, one_b + CCH, ybuf, g, s);
}

// ---------------------------------------------------------------------------
// K2: fused tail+head (R10 structure + dual-MLP: 8 -> 6 serial weight
// phases). grid (8, 8): g2 = head row-group, b = batch. Each block:
// stage 28 L2 cols -> L3 (conv4<10,6>) -> L4 -> L5 -> L6 -> 2 dual-MLP
// phases -> atom rows [g2*448, g2*448+448) (+ pa head in g2==0).
// ---------------------------------------------------------------------------
__global__ void __launch_bounds__(512, 2) k_tail(
        const float* __restrict__ l2c,
        const float* __restrict__ dil_w,
        const float* __restrict__ dil_b,
        const float* __restrict__ one_w,
        const float* __restrict__ one_b,
        const float* __restrict__ aw1, const float* __restrict__ ab1,
        const float* __restrict__ aw2, const float* __restrict__ ab2,
        const float* __restrict__ aw3, const float* __restrict__ ab3,
        const float* __restrict__ pw1, const float* __restrict__ pb1,
        const float* __restrict__ pw2, const float* __restrict__ pb2,
        const float* __restrict__ pw3, const float* __restrict__ pb3,
        float* __restrict__ out)
{
    const int g2  = blockIdx.x;            // head row-group
    const int b   = blockIdx.y;
    const int tid = threadIdx.x;
    const int g   = tid >> 4;
    const int s   = tid & 15;

    __shared__ float E[29][CCH];           // 28 L2 cols + Z
    __shared__ float D[11][CCH];           // 10 L3 cols + Z
    __shared__ float B2[5][CCH];           // L4 {45,46,126,127} + Z
    __shared__ float C2[3][CCH];           // L5 {126,127} + Z
    __shared__ float HF[CCH];              // L6 {127}
    __shared__ float ybuf[10][CCH];
    __shared__ float h1a[CCH], h2a[CCH], h1p[CCH], h2p[CCH];

    if (tid < CCH) { E[28][tid] = 0.f; D[10][tid] = 0.f; B2[4][tid] = 0.f; C2[2][tid] = 0.f; }
    for (int v = tid; v < 28 * 32; v += 512) {
        int col = v >> 5, f4i = v & 31;
        *(float4*)&E[col][f4i * 4] =
            *(const float4*)(l2c + (size_t)(b * 28 + col) * CCH + f4i * 4);
    }

    // L3 (d=9), all 10 cols in one weight phase (6-bit packing)
    conv4<10, 6>(E, D, nullptr,
             PX10(0,1,6,7,12,13,18,19,24,25),
             PX10(2,3,8,9,14,15,20,21,26,27),
             PX10(4,5,10,11,16,17,22,23,28,28),
             PX10(0,1,2,3,4,5,6,7,8,9), -1000,
             dil_w + (size_t)2 * CCH * CCH * 3, dil_b + 2 * CCH,
             one_w + (size_t)2 * CCH * CCH, one_b + 2 * CCH, ybuf, g, s);

    // L4: 45:{18,45,72} 46:{19,46,73} 126:{99,126,Z} 127:{100,127,Z}
    conv4<4>(D, B2, nullptr,
             PK4(0,1,6,7), PK4(2,3,8,9), PK4(4,5,10,10), PK4(0,1,2,3), -1000,
             dil_w + (size_t)3 * CCH * CCH * 3, dil_b + 3 * CCH,
             one_w + (size_t)3 * CCH * CCH, one_b + 3 * CCH, ybuf, g, s);
    // L5: 126:{45,126,Z} 127:{46,127,Z}
    conv4<2>(B2, C2, nullptr,
             PK2(0,1), PK2(2,3), PK2(4,4), PK2(0,1), -1000,
             dil_w + (size_t)4 * CCH * CCH * 3, dil_b + 4 * CCH,
             one_w + (size_t)4 * CCH * CCH, one_b + 4 * CCH, ybuf, g, s);
    // L6: 127:{126,127,Z} -> HF
    conv4<1>(C2, C2, HF,
             PK1(0), PK1(1), PK1(2), PK1(0), -1000,
             dil_w + (size_t)5 * CCH * CCH * 3, dil_b + 5 * CCH,
             one_w + (size_t)5 * CCH * CCH, one_b + 5 * CCH, ybuf, g, s);

    // ---- MLP hidden layers: 2 dual phases (atom + pa together) ----
    mlp4dual(HF,  HF,  h1a, h1p, aw1, ab1, pw1, pb1, tid);
    mlp4dual(h1a, h1p, h2a, h2p, aw2, ab2, pw2, pb2, tid);
    __syncthreads();

    // ---- atom logits: rows [g2*448, g2*448+448) ----
    if (tid < 448) {
        int row = g2 * 448 + tid;
        const float4* r = (const float4*)(aw3 + (size_t)row * CCH);
        float s0 = 0.f, s1 = 0.f, s2 = 0.f, s3 = 0.f;
        #pragma unroll
        for (int k = 0; k < 32; k += 4) {
            s0 += dot4(r[k],     *(const float4*)&h2a[4 * k]);
            s1 += dot4(r[k + 1], *(const float4*)&h2a[4 * k + 4]);
            s2 += dot4(r[k + 2], *(const float4*)&h2a[4 * k + 8]);
            s3 += dot4(r[k + 3], *(const float4*)&h2a[4 * k + 12]);
        }
        out[b * NATOMS + row] = s0 + s1 + s2 + s3 + ab3[row];
    } else if (g2 == 0 && tid >= 448 && tid < 448 + 64) {
        // ---- pa head: 2 outputs, K=128 over 64 lanes ----
        int q = tid - 448;
        int row = q >> 5, qq = q & 31;
        float4 w4 = *(const float4*)(pw3 + row * CCH + 4 * qq);
        float4 xv = *(const float4*)(h2p + 4 * qq);
        float acc = dot4(w4, xv);
        acc += __shfl_xor(acc, 1);
        acc += __shfl_xor(acc, 2);
        acc += __shfl_xor(acc, 4);
        acc += __shfl_xor(acc, 8);
        acc += __shfl_xor(acc, 16);
        if (qq == 0) out[NBATCH * NATOMS + b * 2 + row] = acc + pb3[row];
    }
}

// ---------------------------------------------------------------------------
extern "C" void kernel_launch(void* const* d_in, const int* in_sizes, int n_in,
                              void* d_out, int out_size, void* d_ws, size_t ws_size,
                              hipStream_t stream)
{
    const float* x        = (const float*)d_in[0];
    const float* embed_w  = (const float*)d_in[1];
    const float* posamp_w = (const float*)d_in[2];
    const float* posamp_b = (const float*)d_in[3];
    const float* reduce_w = (const float*)d_in[4];
    const float* reduce_b = (const float*)d_in[5];
    const float* dil_w    = (const float*)d_in[6];
    const float* dil_b    = (const float*)d_in[7];
    const float* one_w    = (const float*)d_in[8];
    const float* one_b    = (const float*)d_in[9];
    const float* aw1 = (const float*)d_in[10]; const float* ab1 = (const float*)d_in[11];
    const float* aw2 = (const float*)d_in[12]; const float* ab2 = (const float*)d_in[13];
    const float* aw3 = (const float*)d_in[14]; const float* ab3 = (const float*)d_in[15];
    const float* pw1 = (const float*)d_in[16]; const float* pb1 = (const float*)d_in[17];
    const float* pw2 = (const float*)d_in[18]; const float* pb2 = (const float*)d_in[19];
    const float* pw3 = (const float*)d_in[20]; const float* pb3 = (const float*)d_in[21];

    float* l2c = (float*)d_ws;                 // [8][28][128] = 114 KB

    k_cone<<<dim3(28, NBATCH), dim3(512), 0, stream>>>(
        x, embed_w, posamp_w, posamp_b, reduce_w, reduce_b,
        dil_w, dil_b, one_w, one_b,
        aw1, aw2, pw1, pw2, aw3, l2c);

    k_tail<<<dim3(8, NBATCH), dim3(512), 0, stream>>>(
        l2c, dil_w, dil_b, one_w, one_b,
        aw1, ab1, aw2, ab2, aw3, ab3,
        pw1, pb1, pw2, pb2, pw3, pb3, (float*)d_out);
}